// Round 10
// baseline (3383.403 us; speedup 1.0000x reference)
//
#include <hip/hip_runtime.h>

typedef unsigned short u16;
typedef __attribute__((ext_vector_type(4))) float f32x4;
typedef __attribute__((ext_vector_type(8))) short s16x8;

// ---------- helpers ----------
__device__ __forceinline__ u16 f2bf(float f) {
    union { float f; unsigned u; } v; v.f = f;
    unsigned r = v.u + 0x7FFFu + ((v.u >> 16) & 1u);
    return (u16)(r >> 16);
}

__device__ __forceinline__ void gload_lds16(const u16* g, u16* l) {
    __builtin_amdgcn_global_load_lds(
        (const __attribute__((address_space(1))) unsigned int*)(g),
        (__attribute__((address_space(3))) unsigned int*)(l),
        16, 0, 0);
}

// ---------- constants ----------
#define NTOK 9216      // B*N = 16*576
#define SEQ  576
#define DMODEL 768
#define DFF  3072
#define NHEAD 12
#define HDIM 64

// ---------- convert f32 -> bf16 ----------
__global__ __launch_bounds__(256) void convert_bf16_kernel(const float* __restrict__ in,
                                                           u16* __restrict__ out, int n) {
    for (int i = blockIdx.x * 256 + threadIdx.x; i < n; i += gridDim.x * 256)
        out[i] = f2bf(in[i]);
}

// ---------- copy f32 ----------
__global__ __launch_bounds__(256) void copy_f32_kernel(const float* __restrict__ in,
                                                       float* __restrict__ out, int n4) {
    const float4* a = (const float4*)in;
    float4* o = (float4*)out;
    for (int i = blockIdx.x * 256 + threadIdx.x; i < n4; i += gridDim.x * 256)
        o[i] = a[i];
}

// ---------- im2col ----------
__global__ __launch_bounds__(256) void im2col_kernel(const float* __restrict__ x,
                                                     u16* __restrict__ out) {
    int tok = blockIdx.x;
    int b = tok / SEQ, n = tok % SEQ;
    int gy = n / 24, gx = n % 24;
    int tid = threadIdx.x;
#pragma unroll
    for (int j = 0; j < 3; ++j) {
        int col = tid + j * 256;
        int c = col >> 8, py = (col >> 4) & 15, px = col & 15;
        float v = x[(size_t)((b * 3 + c) * 384 + gy * 16 + py) * 384 + gx * 16 + px];
        out[(size_t)tok * DMODEL + col] = f2bf(v);
    }
}

// ---------- fast weight transpose: 64x64 tiles, float4 loads, packed stores ----------
__global__ __launch_bounds__(256) void transpose64_kernel(
        const float* __restrict__ qw, const float* __restrict__ kw, const float* __restrict__ vw,
        const float* __restrict__ w1, const float* __restrict__ w2,
        u16* __restrict__ wTq, u16* __restrict__ wTk, u16* __restrict__ wTv,
        u16* __restrict__ w1T, u16* __restrict__ w2T) {
    int bid = blockIdx.x;
    const float* src; u16* dst; int Kd, Nd, tile;
    if (bid < 432)       { int m = bid / 144; src = m == 0 ? qw : (m == 1 ? kw : vw);
                           dst = m == 0 ? wTq : (m == 1 ? wTk : wTv); Kd = 768; Nd = 768; tile = bid % 144; }
    else if (bid < 1008) { src = w1; dst = w1T; Kd = 768; Nd = 3072; tile = bid - 432; }
    else                 { src = w2; dst = w2T; Kd = 3072; Nd = 768; tile = bid - 1008; }
    int ntx = Nd >> 6;
    int tk = (tile / ntx) << 6, tn = (tile % ntx) << 6;
    __shared__ float ts[64][65];
    int tx4 = threadIdx.x & 15, ty = threadIdx.x >> 4;   // 16 float4/row, 16 rows/pass
#pragma unroll
    for (int j = 0; j < 64; j += 16) {
        float4 v = *(const float4*)&src[(size_t)(tk + ty + j) * Nd + tn + tx4 * 4];
        ts[ty + j][tx4 * 4 + 0] = v.x;
        ts[ty + j][tx4 * 4 + 1] = v.y;
        ts[ty + j][tx4 * 4 + 2] = v.z;
        ts[ty + j][tx4 * 4 + 3] = v.w;
    }
    __syncthreads();
    int kx = threadIdx.x & 31, ry = threadIdx.x >> 5;    // 32 u32/row, 8 rows/pass
#pragma unroll
    for (int j = 0; j < 64; j += 8) {
        int r = ry + j;
        unsigned lo = f2bf(ts[2 * kx][r]);
        unsigned hi = f2bf(ts[2 * kx + 1][r]);
        *(unsigned*)&dst[(size_t)(tn + r) * Kd + tk + 2 * kx] = lo | (hi << 16);
    }
}

// ---------- LN (row=768) -> bf16 ----------
__global__ __launch_bounds__(256) void ln_bf16_kernel(const float* __restrict__ X,
                                                      const float* __restrict__ w,
                                                      const float* __restrict__ b,
                                                      u16* __restrict__ Y) {
    int row = blockIdx.x, tid = threadIdx.x;
    const float* x = X + (size_t)row * DMODEL;
    float v0 = x[tid], v1 = x[tid + 256], v2 = x[tid + 512];
    float s = v0 + v1 + v2, sq = v0 * v0 + v1 * v1 + v2 * v2;
#pragma unroll
    for (int off = 32; off >= 1; off >>= 1) { s += __shfl_down(s, off); sq += __shfl_down(sq, off); }
    __shared__ float red[8];
    if ((tid & 63) == 0) { red[tid >> 6] = s; red[4 + (tid >> 6)] = sq; }
    __syncthreads();
    float S = red[0] + red[1] + red[2] + red[3];
    float Q = red[4] + red[5] + red[6] + red[7];
    float mean = S * (1.f / DMODEL);
    float var = Q * (1.f / DMODEL) - mean * mean;
    float inv = rsqrtf(var + 1e-5f);
    u16* y = Y + (size_t)row * DMODEL;
    y[tid]       = f2bf((v0 - mean) * inv * w[tid]       + b[tid]);
    y[tid + 256] = f2bf((v1 - mean) * inv * w[tid + 256] + b[tid + 256]);
    y[tid + 512] = f2bf((v2 - mean) * inv * w[tid + 512] + b[tid + 512]);
}

// ---------- LN in place + add pos ----------
__global__ __launch_bounds__(256) void ln_add_pos_kernel(float* __restrict__ T,
                                                         const float* __restrict__ w,
                                                         const float* __restrict__ b,
                                                         const float* __restrict__ posln) {
    int row = blockIdx.x, tid = threadIdx.x;
    float* x = T + (size_t)row * DMODEL;
    const float* p = posln + (size_t)(row % SEQ) * DMODEL;
    float v0 = x[tid], v1 = x[tid + 256], v2 = x[tid + 512];
    float s = v0 + v1 + v2, sq = v0 * v0 + v1 * v1 + v2 * v2;
#pragma unroll
    for (int off = 32; off >= 1; off >>= 1) { s += __shfl_down(s, off); sq += __shfl_down(sq, off); }
    __shared__ float red[8];
    if ((tid & 63) == 0) { red[tid >> 6] = s; red[4 + (tid >> 6)] = sq; }
    __syncthreads();
    float S = red[0] + red[1] + red[2] + red[3];
    float Q = red[4] + red[5] + red[6] + red[7];
    float mean = S * (1.f / DMODEL);
    float var = Q * (1.f / DMODEL) - mean * mean;
    float inv = rsqrtf(var + 1e-5f);
    x[tid]       = (v0 - mean) * inv * w[tid]       + b[tid]       + p[tid];
    x[tid + 256] = (v1 - mean) * inv * w[tid + 256] + b[tid + 256] + p[tid + 256];
    x[tid + 512] = (v2 - mean) * inv * w[tid + 512] + b[tid + 512] + p[tid + 512];
}

// ---------- pos embedding ----------
__global__ __launch_bounds__(256) void pos_ln_kernel(const float* __restrict__ py,
                                                     const float* __restrict__ px,
                                                     const float* __restrict__ w,
                                                     const float* __restrict__ b,
                                                     const int* __restrict__ xs_p,
                                                     const int* __restrict__ ys_p,
                                                     float* __restrict__ posln,
                                                     float* __restrict__ out2) {
    int row = blockIdx.x;
    int gy = row / 24, gx = row % 24;
    int ys = ys_p[0], xs = xs_p[0];
    int tid = threadIdx.x;
    float v[3]; float s = 0.f, sq = 0.f;
#pragma unroll
    for (int j = 0; j < 3; ++j) {
        int c = tid + j * 256;
        v[j] = py[(size_t)(gy + ys) * DMODEL + c] + px[(size_t)(gx + xs) * DMODEL + c];
        s += v[j]; sq += v[j] * v[j];
    }
#pragma unroll
    for (int off = 32; off >= 1; off >>= 1) { s += __shfl_down(s, off); sq += __shfl_down(sq, off); }
    __shared__ float red[8];
    if ((tid & 63) == 0) { red[tid >> 6] = s; red[4 + (tid >> 6)] = sq; }
    __syncthreads();
    float S = red[0] + red[1] + red[2] + red[3];
    float Q = red[4] + red[5] + red[6] + red[7];
    float mean = S * (1.f / DMODEL);
    float var = Q * (1.f / DMODEL) - mean * mean;
    float inv = rsqrtf(var + 1e-5f);
#pragma unroll
    for (int j = 0; j < 3; ++j) {
        int c = tid + j * 256;
        float y = (v[j] - mean) * inv * w[c] + b[c];
        posln[(size_t)row * DMODEL + c] = y;
        for (int bb = 0; bb < 16; ++bb)
            out2[((size_t)bb * SEQ + row) * DMODEL + c] = y;
    }
}

// ---------- epilogue ids ----------
#define EPI_CONV 0
#define EPI_QKV  1
#define EPI_FFN1 3
#define EPI_FFN2 4

// ---------- gemm97: faithful m97 pattern. 128x128, 4 waves, BK=32, ----------
// SINGLE 16KB LDS buffer, two __syncthreads per K-tile, NO inline asm:
// the compiler emits fine-grained lgkmcnt(7..0) so MFMA overlaps the
// fragment reads (the stall my manual lgkmcnt(0)+sched_barrier created).
// 3 blocks/CU (48KB LDS, launch_bounds(256,3)) cover the vmcnt(0) drain.
template <int EPI>
__global__ __launch_bounds__(256, 3) void gemm97(const u16* __restrict__ A,
                                                 const u16* __restrict__ Bt,
                                                 float* __restrict__ outF,
                                                 u16* __restrict__ outB,
                                                 u16* __restrict__ outB2,
                                                 u16* __restrict__ outB3,
                                                 const float* __restrict__ bias,
                                                 int lda, int N, int K) {
    __shared__ __align__(16) u16 lds[8192];        // A [128][32] + B [128][32]
    const int tid = threadIdx.x;
    const int wave = tid >> 6, lane = tid & 63;
    const int c_lo = lane & 15, c_hi = lane >> 4;
    const int wm = wave >> 1, wn = wave & 1;
    const int m0 = blockIdx.x * 128, n0 = blockIdx.y * 128;
    const int NT = K >> 5;

    // staging source: pre-swizzled column (involution of the read-side XOR)
    const int srow = tid >> 2;                                     // 0..63
    const int koff = ((tid & 3) * 8) ^ (((tid >> 3) & 3) << 3);    // u16 units
    const u16* pA0 = A  + (size_t)(m0 + srow) * lda + koff;
    const u16* pA1 = pA0 + (size_t)64 * lda;
    const u16* pB0 = Bt + (size_t)(n0 + srow) * lda + koff;
    const u16* pB1 = pB0 + (size_t)64 * lda;
    f32x4 acc[4][4] = {};

    const int colA = (c_hi * 8) ^ (((c_lo >> 1) & 3) << 3);        // u16 units

    for (int t = 0; t < NT; ++t) {
        int k0 = t << 5;
        __syncthreads();                            // prev tile's readers done
        gload_lds16(pA0 + k0, lds + tid * 8);
        gload_lds16(pA1 + k0, lds + 2048 + tid * 8);
        gload_lds16(pB0 + k0, lds + 4096 + tid * 8);
        gload_lds16(pB1 + k0, lds + 6144 + tid * 8);
        __syncthreads();                            // compiler drains vmcnt here
        s16x8 af[4], bf[4];
#pragma unroll
        for (int m = 0; m < 4; ++m)
            af[m] = *(const s16x8*)(lds + (wm * 64 + m * 16 + c_lo) * 32 + colA);
#pragma unroll
        for (int n = 0; n < 4; ++n)
            bf[n] = *(const s16x8*)(lds + 4096 + (wn * 64 + n * 16 + c_lo) * 32 + colA);
#pragma unroll
        for (int m = 0; m < 4; ++m)
#pragma unroll
            for (int n = 0; n < 4; ++n)
                acc[m][n] = __builtin_amdgcn_mfma_f32_16x16x32_bf16(af[m], bf[n], acc[m][n], 0, 0, 0);
    }

#pragma unroll
    for (int mf = 0; mf < 4; ++mf)
#pragma unroll
        for (int nf = 0; nf < 4; ++nf)
#pragma unroll
            for (int rr = 0; rr < 4; ++rr) {
                int grow = m0 + wm * 64 + mf * 16 + c_hi * 4 + rr;
                int gcol = n0 + wn * 64 + nf * 16 + c_lo;
                float v = acc[mf][nf][rr];
                if (EPI == EPI_CONV) {
                    v += bias[gcol]; v = fmaxf(v, 0.f);
                    outF[(size_t)grow * 768 + gcol] = v;
                } else if (EPI == EPI_QKV) {
                    int sel = n0 / 768;
                    int lcol = gcol - sel * 768;
                    if (sel == 0)      outB [(size_t)grow * 768 + lcol] = f2bf(v);
                    else if (sel == 1) outB2[(size_t)grow * 768 + lcol] = f2bf(v);
                    else {
                        int b = grow / SEQ, nt = grow % SEQ;
                        int h = lcol >> 6, dh = lcol & 63;
                        outB3[(size_t)(((b * NHEAD + h) << 6) + dh) * SEQ + nt] = f2bf(v);
                    }
                } else if (EPI == EPI_FFN1) {
                    v += bias[gcol]; v = fmaxf(v, 0.f);
                    outB[(size_t)grow * N + gcol] = f2bf(v);
                } else if (EPI == EPI_FFN2) {
                    outF[(size_t)grow * 768 + gcol] += v + bias[gcol];
                }
            }
}

// ---------- flash attention (K/V register double-buffer + XCD grouping) ----------
__global__ __launch_bounds__(256) void attn_kernel(const u16* __restrict__ Qb,
                                                   const u16* __restrict__ Kb,
                                                   const u16* __restrict__ Vt,
                                                   float* __restrict__ T) {
    int bid = blockIdx.x;
    int qt = bid / 192, bh = bid % 192;
    int b = bh / NHEAD, h = bh % NHEAD;
    int q0 = qt * 64;
    const int tid = threadIdx.x, wave = tid >> 6, lane = tid & 63;
    const int c_lo = lane & 15, c_hi = lane >> 4;
    __shared__ __align__(16) u16 Qs[64][72];
    __shared__ __align__(16) u16 Ks[64][72];
    __shared__ __align__(16) u16 Vs[64][72];
    __shared__ __align__(16) u16 Ps[4][16][72];
#pragma unroll
    for (int i = 0; i < 2; ++i) {
        int c = i * 256 + tid, row = c >> 3, slot = (c & 7) * 8;
        *(s16x8*)&Qs[row][slot] =
            *(const s16x8*)(Qb + ((size_t)(b * SEQ + q0 + row) * DMODEL + h * HDIM + slot));
    }
    s16x8 kreg[2], vreg[2];
    {
#pragma unroll
        for (int i = 0; i < 2; ++i) {
            int c = i * 256 + tid, row = c >> 3, slot = (c & 7) * 8;
            kreg[i] = *(const s16x8*)(Kb + ((size_t)(b * SEQ + row) * DMODEL + h * HDIM + slot));
            vreg[i] = *(const s16x8*)(Vt + ((size_t)((b * NHEAD + h) * HDIM + row) * SEQ + slot));
        }
    }
    f32x4 o[4] = {};
    float mrun[4], lrun[4];
#pragma unroll
    for (int r = 0; r < 4; ++r) { mrun[r] = -1e30f; lrun[r] = 0.f; }
    for (int t2 = 0; t2 < 9; ++t2) {
        __builtin_amdgcn_s_barrier();
#pragma unroll
        for (int i = 0; i < 2; ++i) {
            int c = i * 256 + tid, row = c >> 3, slot = (c & 7) * 8;
            *(s16x8*)&Ks[row][slot] = kreg[i];
            *(s16x8*)&Vs[row][slot] = vreg[i];
        }
        asm volatile("s_waitcnt lgkmcnt(0)" ::: "memory");
        __builtin_amdgcn_s_barrier();
        __builtin_amdgcn_sched_barrier(0);
        if (t2 < 8) {
            int kv0 = (t2 + 1) * 64;
#pragma unroll
            for (int i = 0; i < 2; ++i) {
                int c = i * 256 + tid, row = c >> 3, slot = (c & 7) * 8;
                kreg[i] = *(const s16x8*)(Kb + ((size_t)(b * SEQ + kv0 + row) * DMODEL + h * HDIM + slot));
                vreg[i] = *(const s16x8*)(Vt + ((size_t)((b * NHEAD + h) * HDIM + row) * SEQ + kv0 + slot));
            }
        }
        f32x4 s[4] = {};
        s16x8 aq[2];
#pragma unroll
        for (int ks = 0; ks < 2; ++ks)
            aq[ks] = *(const s16x8*)&Qs[wave * 16 + c_lo][ks * 32 + c_hi * 8];
#pragma unroll
        for (int nf = 0; nf < 4; ++nf)
#pragma unroll
            for (int ks = 0; ks < 2; ++ks) {
                s16x8 bk = *(const s16x8*)&Ks[nf * 16 + c_lo][ks * 32 + c_hi * 8];
                s[nf] = __builtin_amdgcn_mfma_f32_16x16x32_bf16(aq[ks], bk, s[nf], 0, 0, 0);
            }
#pragma unroll
        for (int nf = 0; nf < 4; ++nf)
#pragma unroll
            for (int r = 0; r < 4; ++r) s[nf][r] *= 0.125f;
        float mx[4];
#pragma unroll
        for (int r = 0; r < 4; ++r)
            mx[r] = fmaxf(fmaxf(s[0][r], s[1][r]), fmaxf(s[2][r], s[3][r]));
#pragma unroll
        for (int off = 1; off < 16; off <<= 1)
#pragma unroll
            for (int r = 0; r < 4; ++r) mx[r] = fmaxf(mx[r], __shfl_xor(mx[r], off));
        float alpha[4];
#pragma unroll
        for (int r = 0; r < 4; ++r) {
            float mn = fmaxf(mrun[r], mx[r]);
            alpha[r] = __expf(mrun[r] - mn);
            mrun[r] = mn;
            lrun[r] *= alpha[r];
        }
        float ls[4] = {0.f, 0.f, 0.f, 0.f};
        u16 pb[4][4];
#pragma unroll
        for (int nf = 0; nf < 4; ++nf)
#pragma unroll
            for (int r = 0; r < 4; ++r) {
                float p = __expf(s[nf][r] - mrun[r]);
                ls[r] += p;
                pb[nf][r] = f2bf(p);
            }
#pragma unroll
        for (int off = 1; off < 16; off <<= 1)
#pragma unroll
            for (int r = 0; r < 4; ++r) ls[r] += __shfl_xor(ls[r], off);
#pragma unroll
        for (int r = 0; r < 4; ++r) lrun[r] += ls[r];
#pragma unroll
        for (int df = 0; df < 4; ++df)
#pragma unroll
            for (int r = 0; r < 4; ++r) o[df][r] *= alpha[r];
#pragma unroll
        for (int nf = 0; nf < 4; ++nf)
#pragma unroll
            for (int r = 0; r < 4; ++r)
                Ps[wave][c_hi * 4 + r][c_lo + nf * 16] = pb[nf][r];
        asm volatile("s_waitcnt lgkmcnt(0)" ::: "memory");
        s16x8 pa[2];
#pragma unroll
        for (int ks = 0; ks < 2; ++ks)
            pa[ks] = *(const s16x8*)&Ps[wave][c_lo][ks * 32 + c_hi * 8];
#pragma unroll
        for (int df = 0; df < 4; ++df)
#pragma unroll
            for (int ks = 0; ks < 2; ++ks) {
                s16x8 bv = *(const s16x8*)&Vs[df * 16 + c_lo][ks * 32 + c_hi * 8];
                o[df] = __builtin_amdgcn_mfma_f32_16x16x32_bf16(pa[ks], bv, o[df], 0, 0, 0);
            }
    }
#pragma unroll
    for (int df = 0; df < 4; ++df)
#pragma unroll
        for (int r = 0; r < 4; ++r) {
            int grow = b * SEQ + q0 + wave * 16 + c_hi * 4 + r;
            int gcol = h * HDIM + df * 16 + c_lo;
            T[(size_t)grow * DMODEL + gcol] += o[df][r] / lrun[r];
        }
}

// ---------- host ----------
extern "C" void kernel_launch(void* const* d_in, const int* in_sizes, int n_in,
                              void* d_out, int out_size, void* d_ws, size_t ws_size,
                              hipStream_t stream) {
    (void)in_sizes; (void)n_in; (void)out_size; (void)ws_size;
    const float* x        = (const float*)d_in[0];
    const float* conv_w   = (const float*)d_in[1];
    const float* conv_b   = (const float*)d_in[2];
    const float* ln_w     = (const float*)d_in[3];
    const float* ln_b     = (const float*)d_in[4];
    const float* pos_y    = (const float*)d_in[5];
    const float* pos_x    = (const float*)d_in[6];
    const float* mha_ln_w = (const float*)d_in[7];
    const float* mha_ln_b = (const float*)d_in[8];
    const float* qw       = (const float*)d_in[9];
    const float* kw       = (const float*)d_in[10];
    const float* vw       = (const float*)d_in[11];
    const float* ffn_ln_w = (const float*)d_in[12];
    const float* ffn_ln_b = (const float*)d_in[13];
    const float* w1       = (const float*)d_in[14];
    const float* b1       = (const float*)d_in[15];
    const float* w2       = (const float*)d_in[16];
    const float* b2       = (const float*)d_in[17];
    const int*   xs       = (const int*)d_in[18];
    const int*   ys       = (const int*)d_in[19];
    float* out1 = (float*)d_out;
    float* out2 = out1 + (size_t)NTOK * DMODEL;

    size_t off = 0;
    char* ws = (char*)d_ws;
    auto carve = [&](size_t bytes) { char* p = ws + off; off += (bytes + 255) & ~(size_t)255; return p; };
    u16* wTqkv = (u16*)carve((size_t)3 * 768 * 768 * 2);
    u16* w1T = (u16*)carve((size_t)DFF * DMODEL * 2);
    u16* w2T = (u16*)carve((size_t)DMODEL * DFF * 2);
    float* t  = (float*)carve((size_t)NTOK * DMODEL * 4);
    u16* tl   = (u16*)carve((size_t)NTOK * DMODEL * 2);
    u16* qb   = (u16*)carve((size_t)NTOK * DMODEL * 2);
    u16* kb   = (u16*)carve((size_t)NTOK * DMODEL * 2);
    u16* vT   = (u16*)carve((size_t)NTOK * DMODEL * 2);
    u16* hb   = (u16*)carve((size_t)NTOK * DFF * 2);
    float* posln = (float*)carve((size_t)SEQ * DMODEL * 4);
    u16* wTq = wTqkv;
    u16* wTk = wTqkv + (size_t)768 * 768;
    u16* wTv = wTqkv + (size_t)2 * 768 * 768;
    u16* cw   = wTqkv;  // alias: conv weight bf16 (pre-loop only)
    u16* im2c = hb;     // alias: im2col (pre-loop only)

    convert_bf16_kernel<<<1152, 256, 0, stream>>>(conv_w, cw, 768 * 768);
    im2col_kernel<<<NTOK, 256, 0, stream>>>(x, im2c);
    gemm97<EPI_CONV><<<dim3(72, 6), 256, 0, stream>>>(im2c, cw, t, nullptr, nullptr, nullptr,
                                                      conv_b, 768, 768, 768);
    pos_ln_kernel<<<SEQ, 256, 0, stream>>>(pos_y, pos_x, ln_w, ln_b, xs, ys, posln, out2);
    ln_add_pos_kernel<<<NTOK, 256, 0, stream>>>(t, ln_w, ln_b, posln);

    for (int i = 0; i < 12; ++i) {
        transpose64_kernel<<<1584, 256, 0, stream>>>(
            qw + (size_t)i * 768 * 768, kw + (size_t)i * 768 * 768, vw + (size_t)i * 768 * 768,
            w1 + (size_t)i * 768 * DFF, w2 + (size_t)i * DFF * 768,
            wTq, wTk, wTv, w1T, w2T);
        ln_bf16_kernel<<<NTOK, 256, 0, stream>>>(t, mha_ln_w + i * DMODEL, mha_ln_b + i * DMODEL, tl);
        gemm97<EPI_QKV><<<dim3(72, 18), 256, 0, stream>>>(tl, wTqkv, nullptr, qb, kb, vT,
                                                          nullptr, 768, 2304, 768);
        attn_kernel<<<16 * NHEAD * 9, 256, 0, stream>>>(qb, kb, vT, t);
        ln_bf16_kernel<<<NTOK, 256, 0, stream>>>(t, ffn_ln_w + i * DMODEL, ffn_ln_b + i * DMODEL, tl);
        gemm97<EPI_FFN1><<<dim3(72, 24), 256, 0, stream>>>(tl, w1T, nullptr, hb, nullptr, nullptr,
                                                           b1 + (size_t)i * DFF, 768, 3072, 768);
        gemm97<EPI_FFN2><<<dim3(72, 6), 256, 0, stream>>>(hb, w2T, t, nullptr, nullptr, nullptr,
                                                          b2 + (size_t)i * DMODEL, 3072, 768, 3072);
    }
    copy_f32_kernel<<<2048, 256, 0, stream>>>(t, out1, (NTOK * DMODEL) / 4);
}

// Round 11
// 3316.636 us; speedup vs baseline: 1.0201x; 1.0201x over previous
//
#include <hip/hip_runtime.h>

typedef unsigned short u16;
typedef __attribute__((ext_vector_type(4))) float f32x4;
typedef __attribute__((ext_vector_type(8))) short s16x8;

// ---------- helpers ----------
__device__ __forceinline__ u16 f2bf(float f) {
    union { float f; unsigned u; } v; v.f = f;
    unsigned r = v.u + 0x7FFFu + ((v.u >> 16) & 1u);
    return (u16)(r >> 16);
}

__device__ __forceinline__ void gload_lds16(const u16* g, u16* l) {
    __builtin_amdgcn_global_load_lds(
        (const __attribute__((address_space(1))) unsigned int*)(g),
        (__attribute__((address_space(3))) unsigned int*)(l),
        16, 0, 0);
}

// ---------- constants ----------
#define NTOK 9216      // B*N = 16*576
#define SEQ  576
#define DMODEL 768
#define DFF  3072
#define NHEAD 12
#define HDIM 64

// ---------- convert f32 -> bf16 ----------
__global__ __launch_bounds__(256) void convert_bf16_kernel(const float* __restrict__ in,
                                                           u16* __restrict__ out, int n) {
    for (int i = blockIdx.x * 256 + threadIdx.x; i < n; i += gridDim.x * 256)
        out[i] = f2bf(in[i]);
}

// ---------- copy f32 ----------
__global__ __launch_bounds__(256) void copy_f32_kernel(const float* __restrict__ in,
                                                       float* __restrict__ out, int n4) {
    const float4* a = (const float4*)in;
    float4* o = (float4*)out;
    for (int i = blockIdx.x * 256 + threadIdx.x; i < n4; i += gridDim.x * 256)
        o[i] = a[i];
}

// ---------- im2col ----------
__global__ __launch_bounds__(256) void im2col_kernel(const float* __restrict__ x,
                                                     u16* __restrict__ out) {
    int tok = blockIdx.x;
    int b = tok / SEQ, n = tok % SEQ;
    int gy = n / 24, gx = n % 24;
    int tid = threadIdx.x;
#pragma unroll
    for (int j = 0; j < 3; ++j) {
        int col = tid + j * 256;
        int c = col >> 8, py = (col >> 4) & 15, px = col & 15;
        float v = x[(size_t)((b * 3 + c) * 384 + gy * 16 + py) * 384 + gx * 16 + px];
        out[(size_t)tok * DMODEL + col] = f2bf(v);
    }
}

// ---------- fast weight transpose: 64x64 tiles, float4 loads, packed stores ----------
__global__ __launch_bounds__(256) void transpose64_kernel(
        const float* __restrict__ qw, const float* __restrict__ kw, const float* __restrict__ vw,
        const float* __restrict__ w1, const float* __restrict__ w2,
        u16* __restrict__ wTq, u16* __restrict__ wTk, u16* __restrict__ wTv,
        u16* __restrict__ w1T, u16* __restrict__ w2T) {
    int bid = blockIdx.x;
    const float* src; u16* dst; int Kd, Nd, tile;
    if (bid < 432)       { int m = bid / 144; src = m == 0 ? qw : (m == 1 ? kw : vw);
                           dst = m == 0 ? wTq : (m == 1 ? wTk : wTv); Kd = 768; Nd = 768; tile = bid % 144; }
    else if (bid < 1008) { src = w1; dst = w1T; Kd = 768; Nd = 3072; tile = bid - 432; }
    else                 { src = w2; dst = w2T; Kd = 3072; Nd = 768; tile = bid - 1008; }
    int ntx = Nd >> 6;
    int tk = (tile / ntx) << 6, tn = (tile % ntx) << 6;
    __shared__ float ts[64][65];
    int tx4 = threadIdx.x & 15, ty = threadIdx.x >> 4;
#pragma unroll
    for (int j = 0; j < 64; j += 16) {
        float4 v = *(const float4*)&src[(size_t)(tk + ty + j) * Nd + tn + tx4 * 4];
        ts[ty + j][tx4 * 4 + 0] = v.x;
        ts[ty + j][tx4 * 4 + 1] = v.y;
        ts[ty + j][tx4 * 4 + 2] = v.z;
        ts[ty + j][tx4 * 4 + 3] = v.w;
    }
    __syncthreads();
    int kx = threadIdx.x & 31, ry = threadIdx.x >> 5;
#pragma unroll
    for (int j = 0; j < 64; j += 8) {
        int r = ry + j;
        unsigned lo = f2bf(ts[2 * kx][r]);
        unsigned hi = f2bf(ts[2 * kx + 1][r]);
        *(unsigned*)&dst[(size_t)(tn + r) * Kd + tk + 2 * kx] = lo | (hi << 16);
    }
}

// ---------- LN (row=768) -> bf16 ----------
__global__ __launch_bounds__(256) void ln_bf16_kernel(const float* __restrict__ X,
                                                      const float* __restrict__ w,
                                                      const float* __restrict__ b,
                                                      u16* __restrict__ Y) {
    int row = blockIdx.x, tid = threadIdx.x;
    const float* x = X + (size_t)row * DMODEL;
    float v0 = x[tid], v1 = x[tid + 256], v2 = x[tid + 512];
    float s = v0 + v1 + v2, sq = v0 * v0 + v1 * v1 + v2 * v2;
#pragma unroll
    for (int off = 32; off >= 1; off >>= 1) { s += __shfl_down(s, off); sq += __shfl_down(sq, off); }
    __shared__ float red[8];
    if ((tid & 63) == 0) { red[tid >> 6] = s; red[4 + (tid >> 6)] = sq; }
    __syncthreads();
    float S = red[0] + red[1] + red[2] + red[3];
    float Q = red[4] + red[5] + red[6] + red[7];
    float mean = S * (1.f / DMODEL);
    float var = Q * (1.f / DMODEL) - mean * mean;
    float inv = rsqrtf(var + 1e-5f);
    u16* y = Y + (size_t)row * DMODEL;
    y[tid]       = f2bf((v0 - mean) * inv * w[tid]       + b[tid]);
    y[tid + 256] = f2bf((v1 - mean) * inv * w[tid + 256] + b[tid + 256]);
    y[tid + 512] = f2bf((v2 - mean) * inv * w[tid + 512] + b[tid + 512]);
}

// ---------- LN in place + add pos ----------
__global__ __launch_bounds__(256) void ln_add_pos_kernel(float* __restrict__ T,
                                                         const float* __restrict__ w,
                                                         const float* __restrict__ b,
                                                         const float* __restrict__ posln) {
    int row = blockIdx.x, tid = threadIdx.x;
    float* x = T + (size_t)row * DMODEL;
    const float* p = posln + (size_t)(row % SEQ) * DMODEL;
    float v0 = x[tid], v1 = x[tid + 256], v2 = x[tid + 512];
    float s = v0 + v1 + v2, sq = v0 * v0 + v1 * v1 + v2 * v2;
#pragma unroll
    for (int off = 32; off >= 1; off >>= 1) { s += __shfl_down(s, off); sq += __shfl_down(sq, off); }
    __shared__ float red[8];
    if ((tid & 63) == 0) { red[tid >> 6] = s; red[4 + (tid >> 6)] = sq; }
    __syncthreads();
    float S = red[0] + red[1] + red[2] + red[3];
    float Q = red[4] + red[5] + red[6] + red[7];
    float mean = S * (1.f / DMODEL);
    float var = Q * (1.f / DMODEL) - mean * mean;
    float inv = rsqrtf(var + 1e-5f);
    x[tid]       = (v0 - mean) * inv * w[tid]       + b[tid]       + p[tid];
    x[tid + 256] = (v1 - mean) * inv * w[tid + 256] + b[tid + 256] + p[tid + 256];
    x[tid + 512] = (v2 - mean) * inv * w[tid + 512] + b[tid + 512] + p[tid + 512];
}

// ---------- pos embedding ----------
__global__ __launch_bounds__(256) void pos_ln_kernel(const float* __restrict__ py,
                                                     const float* __restrict__ px,
                                                     const float* __restrict__ w,
                                                     const float* __restrict__ b,
                                                     const int* __restrict__ xs_p,
                                                     const int* __restrict__ ys_p,
                                                     float* __restrict__ posln,
                                                     float* __restrict__ out2) {
    int row = blockIdx.x;
    int gy = row / 24, gx = row % 24;
    int ys = ys_p[0], xs = xs_p[0];
    int tid = threadIdx.x;
    float v[3]; float s = 0.f, sq = 0.f;
#pragma unroll
    for (int j = 0; j < 3; ++j) {
        int c = tid + j * 256;
        v[j] = py[(size_t)(gy + ys) * DMODEL + c] + px[(size_t)(gx + xs) * DMODEL + c];
        s += v[j]; sq += v[j] * v[j];
    }
#pragma unroll
    for (int off = 32; off >= 1; off >>= 1) { s += __shfl_down(s, off); sq += __shfl_down(sq, off); }
    __shared__ float red[8];
    if ((tid & 63) == 0) { red[tid >> 6] = s; red[4 + (tid >> 6)] = sq; }
    __syncthreads();
    float S = red[0] + red[1] + red[2] + red[3];
    float Q = red[4] + red[5] + red[6] + red[7];
    float mean = S * (1.f / DMODEL);
    float var = Q * (1.f / DMODEL) - mean * mean;
    float inv = rsqrtf(var + 1e-5f);
#pragma unroll
    for (int j = 0; j < 3; ++j) {
        int c = tid + j * 256;
        float y = (v[j] - mean) * inv * w[c] + b[c];
        posln[(size_t)row * DMODEL + c] = y;
        for (int bb = 0; bb < 16; ++bb)
            out2[((size_t)bb * SEQ + row) * DMODEL + c] = y;
    }
}

// ---------- epilogue ids ----------
#define EPI_CONV 0
#define EPI_QKV  1
#define EPI_FFN1 3
#define EPI_FFN2 4

// ---------- gemmP: 8-phase 256x256 GEMM (R5-verified core, z-split removed) ----------
#define VM4 asm volatile("s_waitcnt vmcnt(4)" ::: "memory")
#define VM0 asm volatile("s_waitcnt vmcnt(0)" ::: "memory")

#define PH(BUF, KS, MH, LOADB, STAGE_STMT, VMCNT_STMT)                                   \
  {                                                                                      \
    if (LOADB) {                                                                         \
      _Pragma("unroll") for (int n = 0; n < 4; ++n)                                      \
        bf[n] = *(const s16x8*)(lds + (BUF)*32768 + (KS)*8192 + fbB + n*512);            \
    }                                                                                    \
    _Pragma("unroll") for (int i = 0; i < 4; ++i)                                        \
      af[i] = *(const s16x8*)(lds + (BUF)*32768 + (KS)*8192 + fbA + (MH)*2048 + i*512);  \
    STAGE_STMT;                                                                          \
    __builtin_amdgcn_s_barrier();                                                        \
    asm volatile("s_waitcnt lgkmcnt(0)" ::: "memory");                                   \
    __builtin_amdgcn_sched_barrier(0);                                                   \
    __builtin_amdgcn_s_setprio(1);                                                       \
    _Pragma("unroll") for (int i = 0; i < 4; ++i)                                        \
      _Pragma("unroll") for (int n = 0; n < 4; ++n)                                      \
        acc[(MH)*4 + i][n] = __builtin_amdgcn_mfma_f32_16x16x32_bf16(                    \
            af[i], bf[n], acc[(MH)*4 + i][n], 0, 0, 0);                                  \
    __builtin_amdgcn_s_setprio(0);                                                       \
    VMCNT_STMT;                                                                          \
    __builtin_amdgcn_s_barrier();                                                        \
    __builtin_amdgcn_sched_barrier(0);                                                   \
  }

template <int EPI, int NT>
__global__ __launch_bounds__(512, 1) void gemmP(const u16* __restrict__ A,
                                                const u16* __restrict__ Bt,
                                                float* __restrict__ outF,
                                                u16* __restrict__ outB,
                                                u16* __restrict__ outB2,
                                                u16* __restrict__ outB3,
                                                const float* __restrict__ bias,
                                                int lda, int N) {
    constexpr int NI = NT / 2;
    __shared__ __align__(16) u16 lds[65536];          // 128 KB
    const int tid = threadIdx.x;
    const int wave = tid >> 6, lane = tid & 63;
    const int c_lo = lane & 15, c_hi = lane >> 4;
    const int wm = wave >> 2, wn = wave & 3;
    const int m0 = blockIdx.x * 256, n0 = blockIdx.y * 256;

    // fragment-read bases (u16 units). swizzle: byte ^= ((row>>1)&3)<<4
    const int sw8 = (((c_lo >> 1) & 3) << 3);
    const int fbA = (wm * 128 + c_lo) * 32 + ((c_hi * 8) ^ sw8);
    const int fbB = 16384 + (wn * 64 + c_lo) * 32 + ((c_hi * 8) ^ sw8);

    // staging: linear LDS dest; pre-swizzled global source (involution)
    const int srow = tid >> 2;                                   // 0..127
    const int koff = ((tid & 3) * 8) ^ (((srow >> 1) & 3) << 3); // elements
    const u16* pA = A + (size_t)(m0 + srow) * lda + koff;
    const u16* pB = Bt + (size_t)(n0 + srow) * lda + koff;
    const size_t rstep = (size_t)128 * lda;

    auto stA = [&](int t, int kh) {
        u16* d = lds + (t & 1) * 32768 + kh * 8192 + tid * 8;
        const u16* s = pA + (size_t)t * 64 + kh * 32;
        gload_lds16(s, d);
        gload_lds16(s + rstep, d + 4096);
    };
    auto stB = [&](int t, int kh) {
        u16* d = lds + 16384 + (t & 1) * 32768 + kh * 8192 + tid * 8;
        const u16* s = pB + (size_t)t * 64 + kh * 32;
        gload_lds16(s, d);
        gload_lds16(s + rstep, d + 4096);
    };

    f32x4 acc[8][4] = {};
    s16x8 af[4], bf[4];

    // prologue: tile0 complete + tile1 Kh0; drain tile0
    stA(0, 0); stB(0, 0); stA(0, 1); stB(0, 1); stA(1, 0); stB(1, 0);
    VM4;
    __builtin_amdgcn_s_barrier();
    __builtin_amdgcn_sched_barrier(0);

    for (int j = 0; j < NI - 1; ++j) {
        const int t1k = 2 * j + 1, t2 = 2 * j + 2, t3 = 2 * j + 3;
        PH(0, 0, 0, true,  { stA(t1k, 1); }, {});   // ph1
        PH(0, 0, 1, false, { stB(t1k, 1); }, {});   // ph2
        PH(0, 1, 0, true,  { stA(t2, 0);  }, {});   // ph3
        PH(0, 1, 1, false, { stB(t2, 0);  }, VM4);  // ph4
        PH(1, 0, 0, true,  { stA(t2, 1);  }, {});   // ph5
        PH(1, 0, 1, false, { stB(t2, 1);  }, {});   // ph6
        PH(1, 1, 0, true,  { stA(t3, 0);  }, {});   // ph7
        PH(1, 1, 1, false, { stB(t3, 0);  }, VM4);  // ph8
    }
    {   // tail iteration: tiles NT-2 (buf0), NT-1 (buf1)
        const int t1k = NT - 1;
        PH(0, 0, 0, true,  { stA(t1k, 1); }, {});
        PH(0, 0, 1, false, { stB(t1k, 1); }, {});
        PH(0, 1, 0, true,  {}, {});
        PH(0, 1, 1, false, {}, VM0);
        PH(1, 0, 0, true,  {}, {});
        PH(1, 0, 1, false, {}, {});
        PH(1, 1, 0, true,  {}, {});
        PH(1, 1, 1, false, {}, {});
    }

#pragma unroll
    for (int mf = 0; mf < 8; ++mf)
#pragma unroll
        for (int nf = 0; nf < 4; ++nf)
#pragma unroll
            for (int rr = 0; rr < 4; ++rr) {
                int grow = m0 + wm * 128 + mf * 16 + c_hi * 4 + rr;
                int gcol = n0 + wn * 64 + nf * 16 + c_lo;
                float v = acc[mf][nf][rr];
                if (EPI == EPI_CONV) {
                    v += bias[gcol]; v = fmaxf(v, 0.f);
                    outF[(size_t)grow * 768 + gcol] = v;
                } else if (EPI == EPI_QKV) {
                    int sel = n0 / 768;
                    int lcol = gcol - sel * 768;
                    if (sel == 0)      outB [(size_t)grow * 768 + lcol] = f2bf(v);
                    else if (sel == 1) outB2[(size_t)grow * 768 + lcol] = f2bf(v);
                    else {
                        int b = grow / SEQ, nt = grow % SEQ;
                        int h = lcol >> 6, dh = lcol & 63;
                        outB3[(size_t)(((b * NHEAD + h) << 6) + dh) * SEQ + nt] = f2bf(v);
                    }
                } else if (EPI == EPI_FFN1) {
                    v += bias[gcol]; v = fmaxf(v, 0.f);
                    outB[(size_t)grow * N + gcol] = f2bf(v);
                }
            }
}

// ---------- gemm3b (128x256, 3-buf, 2 blocks/CU) for FFN2 ----------
template <int EPI>
__global__ __launch_bounds__(512, 4) void gemm3b(const u16* __restrict__ A,
                                                 const u16* __restrict__ Bt,
                                                 float* __restrict__ outF,
                                                 u16* __restrict__ outB,
                                                 const float* __restrict__ bias,
                                                 int lda, int N, int K) {
    __shared__ __align__(16) u16 lds[3 * 12288];
    const int tid = threadIdx.x;
    const int wave = tid >> 6, lane = tid & 63;
    const int c_lo = lane & 15, c_hi = lane >> 4;
    const int wm = wave >> 2, wn = wave & 3;
    const int m0 = blockIdx.x * 128, n0 = blockIdx.y * 256;
    const int NT = K >> 5;

    const int srow = tid >> 2;
    const int koff = ((tid & 3) * 8) ^ (((srow >> 1) & 3) << 3);
    const u16* pA = A  + (size_t)(m0 + srow) * lda + koff;
    const u16* pB = Bt + (size_t)(n0 + srow) * lda + koff;
    const size_t rstepB = (size_t)128 * lda;
    f32x4 acc[4][4] = {};

    auto stage = [&](int t) {
        u16* buf = lds + (t % 3) * 12288;
        int k0 = t << 5;
        gload_lds16(pA + k0, buf + tid * 8);
        gload_lds16(pB + k0, buf + 4096 + tid * 8);
        gload_lds16(pB + rstepB + k0, buf + 8192 + tid * 8);
    };

    stage(0); stage(1);
    asm volatile("s_waitcnt vmcnt(3)" ::: "memory");
    __builtin_amdgcn_s_barrier();
    __builtin_amdgcn_sched_barrier(0);

    const int sw = ((c_lo >> 1) & 3) << 3;
    const int colA = (c_hi * 8) ^ sw;

    for (int t = 0; t < NT; ++t) {
        if (t + 2 < NT) stage(t + 2);
        const u16* buf = lds + (t % 3) * 12288;
        s16x8 af[4], bf[4];
#pragma unroll
        for (int m = 0; m < 4; ++m)
            af[m] = *(const s16x8*)(buf + (wm * 64 + m * 16 + c_lo) * 32 + colA);
#pragma unroll
        for (int n = 0; n < 4; ++n)
            bf[n] = *(const s16x8*)(buf + 4096 + (wn * 64 + n * 16 + c_lo) * 32 + colA);
        asm volatile("s_waitcnt lgkmcnt(0)" ::: "memory");
        __builtin_amdgcn_sched_barrier(0);
        __builtin_amdgcn_s_setprio(1);
#pragma unroll
        for (int m = 0; m < 4; ++m)
#pragma unroll
            for (int n = 0; n < 4; ++n)
                acc[m][n] = __builtin_amdgcn_mfma_f32_16x16x32_bf16(af[m], bf[n], acc[m][n], 0, 0, 0);
        __builtin_amdgcn_s_setprio(0);
        if (t + 2 < NT)      { asm volatile("s_waitcnt vmcnt(3)" ::: "memory"); }
        else if (t + 1 < NT) { asm volatile("s_waitcnt vmcnt(0)" ::: "memory"); }
        __builtin_amdgcn_s_barrier();
        __builtin_amdgcn_sched_barrier(0);
    }

#pragma unroll
    for (int mf = 0; mf < 4; ++mf)
#pragma unroll
        for (int nf = 0; nf < 4; ++nf)
#pragma unroll
            for (int rr = 0; rr < 4; ++rr) {
                int grow = m0 + wm * 64 + mf * 16 + c_hi * 4 + rr;
                int gcol = n0 + wn * 64 + nf * 16 + c_lo;
                float v = acc[mf][nf][rr];
                if (EPI == EPI_FFN2) {
                    outF[(size_t)grow * 768 + gcol] += v + bias[gcol];
                }
            }
}

// ---------- flash attention (K/V register double-buffer + XCD grouping) ----------
__global__ __launch_bounds__(256) void attn_kernel(const u16* __restrict__ Qb,
                                                   const u16* __restrict__ Kb,
                                                   const u16* __restrict__ Vt,
                                                   float* __restrict__ T) {
    int bid = blockIdx.x;
    int qt = bid / 192, bh = bid % 192;
    int b = bh / NHEAD, h = bh % NHEAD;
    int q0 = qt * 64;
    const int tid = threadIdx.x, wave = tid >> 6, lane = tid & 63;
    const int c_lo = lane & 15, c_hi = lane >> 4;
    __shared__ __align__(16) u16 Qs[64][72];
    __shared__ __align__(16) u16 Ks[64][72];
    __shared__ __align__(16) u16 Vs[64][72];
    __shared__ __align__(16) u16 Ps[4][16][72];
#pragma unroll
    for (int i = 0; i < 2; ++i) {
        int c = i * 256 + tid, row = c >> 3, slot = (c & 7) * 8;
        *(s16x8*)&Qs[row][slot] =
            *(const s16x8*)(Qb + ((size_t)(b * SEQ + q0 + row) * DMODEL + h * HDIM + slot));
    }
    s16x8 kreg[2], vreg[2];
    {
#pragma unroll
        for (int i = 0; i < 2; ++i) {
            int c = i * 256 + tid, row = c >> 3, slot = (c & 7) * 8;
            kreg[i] = *(const s16x8*)(Kb + ((size_t)(b * SEQ + row) * DMODEL + h * HDIM + slot));
            vreg[i] = *(const s16x8*)(Vt + ((size_t)((b * NHEAD + h) * HDIM + row) * SEQ + slot));
        }
    }
    f32x4 o[4] = {};
    float mrun[4], lrun[4];
#pragma unroll
    for (int r = 0; r < 4; ++r) { mrun[r] = -1e30f; lrun[r] = 0.f; }
    for (int t2 = 0; t2 < 9; ++t2) {
        __builtin_amdgcn_s_barrier();
#pragma unroll
        for (int i = 0; i < 2; ++i) {
            int c = i * 256 + tid, row = c >> 3, slot = (c & 7) * 8;
            *(s16x8*)&Ks[row][slot] = kreg[i];
            *(s16x8*)&Vs[row][slot] = vreg[i];
        }
        asm volatile("s_waitcnt lgkmcnt(0)" ::: "memory");
        __builtin_amdgcn_s_barrier();
        __builtin_amdgcn_sched_barrier(0);
        if (t2 < 8) {
            int kv0 = (t2 + 1) * 64;
#pragma unroll
            for (int i = 0; i < 2; ++i) {
                int c = i * 256 + tid, row = c >> 3, slot = (c & 7) * 8;
                kreg[i] = *(const s16x8*)(Kb + ((size_t)(b * SEQ + kv0 + row) * DMODEL + h * HDIM + slot));
                vreg[i] = *(const s16x8*)(Vt + ((size_t)((b * NHEAD + h) * HDIM + row) * SEQ + kv0 + slot));
            }
        }
        f32x4 s[4] = {};
        s16x8 aq[2];
#pragma unroll
        for (int ks = 0; ks < 2; ++ks)
            aq[ks] = *(const s16x8*)&Qs[wave * 16 + c_lo][ks * 32 + c_hi * 8];
#pragma unroll
        for (int nf = 0; nf < 4; ++nf)
#pragma unroll
            for (int ks = 0; ks < 2; ++ks) {
                s16x8 bk = *(const s16x8*)&Ks[nf * 16 + c_lo][ks * 32 + c_hi * 8];
                s[nf] = __builtin_amdgcn_mfma_f32_16x16x32_bf16(aq[ks], bk, s[nf], 0, 0, 0);
            }
#pragma unroll
        for (int nf = 0; nf < 4; ++nf)
#pragma unroll
            for (int r = 0; r < 4; ++r) s[nf][r] *= 0.125f;
        float mx[4];
#pragma unroll
        for (int r = 0; r < 4; ++r)
            mx[r] = fmaxf(fmaxf(s[0][r], s[1][r]), fmaxf(s[2][r], s[3][r]));
#pragma unroll
        for (int off = 1; off < 16; off <<= 1)
#pragma unroll
            for (int r = 0; r < 4; ++r) mx[r] = fmaxf(mx[r], __shfl_xor(mx[r], off));
        float alpha[4];
#pragma unroll
        for (int r = 0; r < 4; ++r) {
            float mn = fmaxf(mrun[r], mx[r]);
            alpha[r] = __expf(mrun[r] - mn);
            mrun[r] = mn;
            lrun[r] *= alpha[r];
        }
        float ls[4] = {0.f, 0.f, 0.f, 0.f};
        u16 pb[4][4];
#pragma unroll
        for (int nf = 0; nf < 4; ++nf)
#pragma unroll
            for (int r = 0; r < 4; ++r) {
                float p = __expf(s[nf][r] - mrun[r]);
                ls[r] += p;
                pb[nf][r] = f2bf(p);
            }
#pragma unroll
        for (int off = 1; off < 16; off <<= 1)
#pragma unroll
            for (int r = 0; r < 4; ++r) ls[r] += __shfl_xor(ls[r], off);
#pragma unroll
        for (int r = 0; r < 4; ++r) lrun[r] += ls[r];
#pragma unroll
        for (int df = 0; df < 4; ++df)
#pragma unroll
            for (int r = 0; r < 4; ++r) o[df][r] *= alpha[r];
#pragma unroll
        for (int nf = 0; nf < 4; ++nf)
#pragma unroll
            for (int r = 0; r < 4; ++r)
                Ps[wave][c_hi * 4 + r][c_lo + nf * 16] = pb[nf][r];
        asm volatile("s_waitcnt lgkmcnt(0)" ::: "memory");
        s16x8 pa[2];
#pragma unroll
        for (int ks = 0; ks < 2; ++ks)
            pa[ks] = *(const s16x8*)&Ps[wave][c_lo][ks * 32 + c_hi * 8];
#pragma unroll
        for (int df = 0; df < 4; ++df)
#pragma unroll
            for (int ks = 0; ks < 2; ++ks) {
                s16x8 bv = *(const s16x8*)&Vs[df * 16 + c_lo][ks * 32 + c_hi * 8];
                o[df] = __builtin_amdgcn_mfma_f32_16x16x32_bf16(pa[ks], bv, o[df], 0, 0, 0);
            }
    }
#pragma unroll
    for (int df = 0; df < 4; ++df)
#pragma unroll
        for (int r = 0; r < 4; ++r) {
            int grow = b * SEQ + q0 + wave * 16 + c_hi * 4 + r;
            int gcol = h * HDIM + df * 16 + c_lo;
            T[(size_t)grow * DMODEL + gcol] += o[df][r] / lrun[r];
        }
}

// ---------- host ----------
extern "C" void kernel_launch(void* const* d_in, const int* in_sizes, int n_in,
                              void* d_out, int out_size, void* d_ws, size_t ws_size,
                              hipStream_t stream) {
    (void)in_sizes; (void)n_in; (void)out_size; (void)ws_size;
    const float* x        = (const float*)d_in[0];
    const float* conv_w   = (const float*)d_in[1];
    const float* conv_b   = (const float*)d_in[2];
    const float* ln_w     = (const float*)d_in[3];
    const float* ln_b     = (const float*)d_in[4];
    const float* pos_y    = (const float*)d_in[5];
    const float* pos_x    = (const float*)d_in[6];
    const float* mha_ln_w = (const float*)d_in[7];
    const float* mha_ln_b = (const float*)d_in[8];
    const float* qw       = (const float*)d_in[9];
    const float* kw       = (const float*)d_in[10];
    const float* vw       = (const float*)d_in[11];
    const float* ffn_ln_w = (const float*)d_in[12];
    const float* ffn_ln_b = (const float*)d_in[13];
    const float* w1       = (const float*)d_in[14];
    const float* b1       = (const float*)d_in[15];
    const float* w2       = (const float*)d_in[16];
    const float* b2       = (const float*)d_in[17];
    const int*   xs       = (const int*)d_in[18];
    const int*   ys       = (const int*)d_in[19];
    float* out1 = (float*)d_out;
    float* out2 = out1 + (size_t)NTOK * DMODEL;

    size_t off = 0;
    char* ws = (char*)d_ws;
    auto carve = [&](size_t bytes) { char* p = ws + off; off += (bytes + 255) & ~(size_t)255; return p; };
    u16* wTqkv = (u16*)carve((size_t)3 * 768 * 768 * 2);
    u16* w1T = (u16*)carve((size_t)DFF * DMODEL * 2);
    u16* w2T = (u16*)carve((size_t)DMODEL * DFF * 2);
    float* t  = (float*)carve((size_t)NTOK * DMODEL * 4);
    u16* tl   = (u16*)carve((size_t)NTOK * DMODEL * 2);
    u16* qb   = (u16*)carve((size_t)NTOK * DMODEL * 2);
    u16* kb   = (u16*)carve((size_t)NTOK * DMODEL * 2);
    u16* vT   = (u16*)carve((size_t)NTOK * DMODEL * 2);
    u16* hb   = (u16*)carve((size_t)NTOK * DFF * 2);
    float* posln = (float*)carve((size_t)SEQ * DMODEL * 4);
    u16* wTq = wTqkv;
    u16* wTk = wTqkv + (size_t)768 * 768;
    u16* wTv = wTqkv + (size_t)2 * 768 * 768;
    u16* cw   = wTqkv;  // alias: conv weight bf16 (pre-loop only)
    u16* im2c = hb;     // alias: im2col (pre-loop only)

    convert_bf16_kernel<<<1152, 256, 0, stream>>>(conv_w, cw, 768 * 768);
    im2col_kernel<<<NTOK, 256, 0, stream>>>(x, im2c);
    gemmP<EPI_CONV, 12><<<dim3(36, 3), 512, 0, stream>>>(im2c, cw, t, nullptr, nullptr, nullptr,
                                                         conv_b, 768, 768);
    pos_ln_kernel<<<SEQ, 256, 0, stream>>>(pos_y, pos_x, ln_w, ln_b, xs, ys, posln, out2);
    ln_add_pos_kernel<<<NTOK, 256, 0, stream>>>(t, ln_w, ln_b, posln);

    for (int i = 0; i < 12; ++i) {
        transpose64_kernel<<<1584, 256, 0, stream>>>(
            qw + (size_t)i * 768 * 768, kw + (size_t)i * 768 * 768, vw + (size_t)i * 768 * 768,
            w1 + (size_t)i * 768 * DFF, w2 + (size_t)i * DFF * 768,
            wTq, wTk, wTv, w1T, w2T);
        ln_bf16_kernel<<<NTOK, 256, 0, stream>>>(t, mha_ln_w + i * DMODEL, mha_ln_b + i * DMODEL, tl);
        gemmP<EPI_QKV, 12><<<dim3(36, 9), 512, 0, stream>>>(tl, wTqkv, nullptr, qb, kb, vT,
                                                            nullptr, 768, 2304);
        attn_kernel<<<16 * NHEAD * 9, 256, 0, stream>>>(qb, kb, vT, t);
        ln_bf16_kernel<<<NTOK, 256, 0, stream>>>(t, ffn_ln_w + i * DMODEL, ffn_ln_b + i * DMODEL, tl);
        gemmP<EPI_FFN1, 12><<<dim3(36, 12), 512, 0, stream>>>(tl, w1T, nullptr, hb, nullptr, nullptr,
                                                              b1 + (size_t)i * DFF, 768, 3072);
        gemm3b<EPI_FFN2><<<dim3(72, 3), 512, 0, stream>>>(hb, w2T, t, nullptr,
                                                          b2 + (size_t)i * DMODEL, 3072, 768, 3072);
    }
    copy_f32_kernel<<<2048, 256, 0, stream>>>(t, out1, (NTOK * DMODEL) / 4);
}

// Round 12
// 3109.770 us; speedup vs baseline: 1.0880x; 1.0665x over previous
//
#include <hip/hip_runtime.h>

typedef unsigned short u16;
typedef __attribute__((ext_vector_type(4))) float f32x4;
typedef __attribute__((ext_vector_type(8))) short s16x8;

// ---------- helpers ----------
__device__ __forceinline__ u16 f2bf(float f) {
    union { float f; unsigned u; } v; v.f = f;
    unsigned r = v.u + 0x7FFFu + ((v.u >> 16) & 1u);
    return (u16)(r >> 16);
}

__device__ __forceinline__ void gload_lds16(const u16* g, u16* l) {
    __builtin_amdgcn_global_load_lds(
        (const __attribute__((address_space(1))) unsigned int*)(g),
        (__attribute__((address_space(3))) unsigned int*)(l),
        16, 0, 0);
}

// ---------- constants ----------
#define NTOK 9216      // B*N = 16*576
#define SEQ  576
#define DMODEL 768
#define DFF  3072
#define NHEAD 12
#define HDIM 64

// ---------- convert f32 -> bf16 ----------
__global__ __launch_bounds__(256) void convert_bf16_kernel(const float* __restrict__ in,
                                                           u16* __restrict__ out, int n) {
    for (int i = blockIdx.x * 256 + threadIdx.x; i < n; i += gridDim.x * 256)
        out[i] = f2bf(in[i]);
}

// ---------- copy f32 ----------
__global__ __launch_bounds__(256) void copy_f32_kernel(const float* __restrict__ in,
                                                       float* __restrict__ out, int n4) {
    const float4* a = (const float4*)in;
    float4* o = (float4*)out;
    for (int i = blockIdx.x * 256 + threadIdx.x; i < n4; i += gridDim.x * 256)
        o[i] = a[i];
}

// ---------- im2col ----------
__global__ __launch_bounds__(256) void im2col_kernel(const float* __restrict__ x,
                                                     u16* __restrict__ out) {
    int tok = blockIdx.x;
    int b = tok / SEQ, n = tok % SEQ;
    int gy = n / 24, gx = n % 24;
    int tid = threadIdx.x;
#pragma unroll
    for (int j = 0; j < 3; ++j) {
        int col = tid + j * 256;
        int c = col >> 8, py = (col >> 4) & 15, px = col & 15;
        float v = x[(size_t)((b * 3 + c) * 384 + gy * 16 + py) * 384 + gx * 16 + px];
        out[(size_t)tok * DMODEL + col] = f2bf(v);
    }
}

// ---------- weight transpose: 64x64 tiles, float4 loads, packed stores ----------
// NLAYERS layers in one launch: bid = layer*1584 + inner.
__global__ __launch_bounds__(256) void transpose64_kernel(
        const float* __restrict__ qw0, const float* __restrict__ kw0, const float* __restrict__ vw0,
        const float* __restrict__ w10, const float* __restrict__ w20,
        u16* __restrict__ wTqkv0, u16* __restrict__ w1T0, u16* __restrict__ w2T0,
        size_t wqkv_stride, size_t w1_stride) {
    int layer = blockIdx.x / 1584;
    int bid = blockIdx.x % 1584;
    const float* qw = qw0 + (size_t)layer * 768 * 768;
    const float* kw = kw0 + (size_t)layer * 768 * 768;
    const float* vw = vw0 + (size_t)layer * 768 * 768;
    const float* w1 = w10 + (size_t)layer * 768 * DFF;
    const float* w2 = w20 + (size_t)layer * DFF * 768;
    u16* wTq = wTqkv0 + (size_t)layer * wqkv_stride;
    u16* wTk = wTq + (size_t)768 * 768;
    u16* wTv = wTq + (size_t)2 * 768 * 768;
    u16* w1T = w1T0 + (size_t)layer * w1_stride;
    u16* w2T = w2T0 + (size_t)layer * w1_stride;

    const float* src; u16* dst; int Kd, Nd, tile;
    if (bid < 432)       { int m = bid / 144; src = m == 0 ? qw : (m == 1 ? kw : vw);
                           dst = m == 0 ? wTq : (m == 1 ? wTk : wTv); Kd = 768; Nd = 768; tile = bid % 144; }
    else if (bid < 1008) { src = w1; dst = w1T; Kd = 768; Nd = 3072; tile = bid - 432; }
    else                 { src = w2; dst = w2T; Kd = 3072; Nd = 768; tile = bid - 1008; }
    int ntx = Nd >> 6;
    int tk = (tile / ntx) << 6, tn = (tile % ntx) << 6;
    __shared__ float ts[64][65];
    int tx4 = threadIdx.x & 15, ty = threadIdx.x >> 4;
#pragma unroll
    for (int j = 0; j < 64; j += 16) {
        float4 v = *(const float4*)&src[(size_t)(tk + ty + j) * Nd + tn + tx4 * 4];
        ts[ty + j][tx4 * 4 + 0] = v.x;
        ts[ty + j][tx4 * 4 + 1] = v.y;
        ts[ty + j][tx4 * 4 + 2] = v.z;
        ts[ty + j][tx4 * 4 + 3] = v.w;
    }
    __syncthreads();
    int kx = threadIdx.x & 31, ry = threadIdx.x >> 5;
#pragma unroll
    for (int j = 0; j < 64; j += 8) {
        int r = ry + j;
        unsigned lo = f2bf(ts[2 * kx][r]);
        unsigned hi = f2bf(ts[2 * kx + 1][r]);
        *(unsigned*)&dst[(size_t)(tn + r) * Kd + tk + 2 * kx] = lo | (hi << 16);
    }
}

// ---------- LN (row=768) -> bf16 ----------
__global__ __launch_bounds__(256) void ln_bf16_kernel(const float* __restrict__ X,
                                                      const float* __restrict__ w,
                                                      const float* __restrict__ b,
                                                      u16* __restrict__ Y) {
    int row = blockIdx.x, tid = threadIdx.x;
    const float* x = X + (size_t)row * DMODEL;
    float v0 = x[tid], v1 = x[tid + 256], v2 = x[tid + 512];
    float s = v0 + v1 + v2, sq = v0 * v0 + v1 * v1 + v2 * v2;
#pragma unroll
    for (int off = 32; off >= 1; off >>= 1) { s += __shfl_down(s, off); sq += __shfl_down(sq, off); }
    __shared__ float red[8];
    if ((tid & 63) == 0) { red[tid >> 6] = s; red[4 + (tid >> 6)] = sq; }
    __syncthreads();
    float S = red[0] + red[1] + red[2] + red[3];
    float Q = red[4] + red[5] + red[6] + red[7];
    float mean = S * (1.f / DMODEL);
    float var = Q * (1.f / DMODEL) - mean * mean;
    float inv = rsqrtf(var + 1e-5f);
    u16* y = Y + (size_t)row * DMODEL;
    y[tid]       = f2bf((v0 - mean) * inv * w[tid]       + b[tid]);
    y[tid + 256] = f2bf((v1 - mean) * inv * w[tid + 256] + b[tid + 256]);
    y[tid + 512] = f2bf((v2 - mean) * inv * w[tid + 512] + b[tid + 512]);
}

// ---------- LN in place + add pos ----------
__global__ __launch_bounds__(256) void ln_add_pos_kernel(float* __restrict__ T,
                                                         const float* __restrict__ w,
                                                         const float* __restrict__ b,
                                                         const float* __restrict__ posln) {
    int row = blockIdx.x, tid = threadIdx.x;
    float* x = T + (size_t)row * DMODEL;
    const float* p = posln + (size_t)(row % SEQ) * DMODEL;
    float v0 = x[tid], v1 = x[tid + 256], v2 = x[tid + 512];
    float s = v0 + v1 + v2, sq = v0 * v0 + v1 * v1 + v2 * v2;
#pragma unroll
    for (int off = 32; off >= 1; off >>= 1) { s += __shfl_down(s, off); sq += __shfl_down(sq, off); }
    __shared__ float red[8];
    if ((tid & 63) == 0) { red[tid >> 6] = s; red[4 + (tid >> 6)] = sq; }
    __syncthreads();
    float S = red[0] + red[1] + red[2] + red[3];
    float Q = red[4] + red[5] + red[6] + red[7];
    float mean = S * (1.f / DMODEL);
    float var = Q * (1.f / DMODEL) - mean * mean;
    float inv = rsqrtf(var + 1e-5f);
    x[tid]       = (v0 - mean) * inv * w[tid]       + b[tid]       + p[tid];
    x[tid + 256] = (v1 - mean) * inv * w[tid + 256] + b[tid + 256] + p[tid + 256];
    x[tid + 512] = (v2 - mean) * inv * w[tid + 512] + b[tid + 512] + p[tid + 512];
}

// ---------- pos embedding ----------
__global__ __launch_bounds__(256) void pos_ln_kernel(const float* __restrict__ py,
                                                     const float* __restrict__ px,
                                                     const float* __restrict__ w,
                                                     const float* __restrict__ b,
                                                     const int* __restrict__ xs_p,
                                                     const int* __restrict__ ys_p,
                                                     float* __restrict__ posln,
                                                     float* __restrict__ out2) {
    int row = blockIdx.x;
    int gy = row / 24, gx = row % 24;
    int ys = ys_p[0], xs = xs_p[0];
    int tid = threadIdx.x;
    float v[3]; float s = 0.f, sq = 0.f;
#pragma unroll
    for (int j = 0; j < 3; ++j) {
        int c = tid + j * 256;
        v[j] = py[(size_t)(gy + ys) * DMODEL + c] + px[(size_t)(gx + xs) * DMODEL + c];
        s += v[j]; sq += v[j] * v[j];
    }
#pragma unroll
    for (int off = 32; off >= 1; off >>= 1) { s += __shfl_down(s, off); sq += __shfl_down(sq, off); }
    __shared__ float red[8];
    if ((tid & 63) == 0) { red[tid >> 6] = s; red[4 + (tid >> 6)] = sq; }
    __syncthreads();
    float S = red[0] + red[1] + red[2] + red[3];
    float Q = red[4] + red[5] + red[6] + red[7];
    float mean = S * (1.f / DMODEL);
    float var = Q * (1.f / DMODEL) - mean * mean;
    float inv = rsqrtf(var + 1e-5f);
#pragma unroll
    for (int j = 0; j < 3; ++j) {
        int c = tid + j * 256;
        float y = (v[j] - mean) * inv * w[c] + b[c];
        posln[(size_t)row * DMODEL + c] = y;
        for (int bb = 0; bb < 16; ++bb)
            out2[((size_t)bb * SEQ + row) * DMODEL + c] = y;
    }
}

// ---------- epilogue ids ----------
#define EPI_CONV 0
#define EPI_QKV  1
#define EPI_FFN1 3
#define EPI_FFN2 4

// ---------- gemm3b: 128x256 tile, BK=32, 3 LDS bufs (72KB), swizzled (R7 best) ----------
template <int EPI>
__global__ __launch_bounds__(512, 4) void gemm3b(const u16* __restrict__ A,
                                                 const u16* __restrict__ Bt,
                                                 float* __restrict__ outF,
                                                 u16* __restrict__ outB,
                                                 u16* __restrict__ outB2,
                                                 u16* __restrict__ outB3,
                                                 const float* __restrict__ bias,
                                                 int lda, int N, int K) {
    __shared__ __align__(16) u16 lds[3 * 12288];   // 3 x 24KB (A 8KB + B 16KB)
    const int tid = threadIdx.x;
    const int wave = tid >> 6, lane = tid & 63;
    const int c_lo = lane & 15, c_hi = lane >> 4;
    const int wm = wave >> 2, wn = wave & 3;
    const int m0 = blockIdx.x * 128, n0 = blockIdx.y * 256;
    const int NT = K >> 5;

    // staging source: pre-swizzled column (involution of the read-side XOR)
    const int srow = tid >> 2;                                     // 0..127
    const int koff = ((tid & 3) * 8) ^ (((srow >> 1) & 3) << 3);   // u16 units
    const u16* pA = A  + (size_t)(m0 + srow) * lda + koff;
    const u16* pB = Bt + (size_t)(n0 + srow) * lda + koff;
    const size_t rstepB = (size_t)128 * lda;
    f32x4 acc[4][4] = {};

    auto stage = [&](int t) {
        u16* buf = lds + (t % 3) * 12288;
        int k0 = t << 5;
        gload_lds16(pA + k0, buf + tid * 8);
        gload_lds16(pB + k0, buf + 4096 + tid * 8);
        gload_lds16(pB + rstepB + k0, buf + 8192 + tid * 8);
    };

    stage(0); stage(1);
    asm volatile("s_waitcnt vmcnt(3)" ::: "memory");
    __builtin_amdgcn_s_barrier();
    __builtin_amdgcn_sched_barrier(0);

    const int sw = ((c_lo >> 1) & 3) << 3;       // u16 units
    const int colA = (c_hi * 8) ^ sw;

    for (int t = 0; t < NT; ++t) {
        if (t + 2 < NT) stage(t + 2);
        const u16* buf = lds + (t % 3) * 12288;
        s16x8 af[4], bf[4];
#pragma unroll
        for (int m = 0; m < 4; ++m)
            af[m] = *(const s16x8*)(buf + (wm * 64 + m * 16 + c_lo) * 32 + colA);
#pragma unroll
        for (int n = 0; n < 4; ++n)
            bf[n] = *(const s16x8*)(buf + 4096 + (wn * 64 + n * 16 + c_lo) * 32 + colA);
        asm volatile("s_waitcnt lgkmcnt(0)" ::: "memory");
        __builtin_amdgcn_sched_barrier(0);
        __builtin_amdgcn_s_setprio(1);
#pragma unroll
        for (int m = 0; m < 4; ++m)
#pragma unroll
            for (int n = 0; n < 4; ++n)
                acc[m][n] = __builtin_amdgcn_mfma_f32_16x16x32_bf16(af[m], bf[n], acc[m][n], 0, 0, 0);
        __builtin_amdgcn_s_setprio(0);
        if (t + 2 < NT)      { asm volatile("s_waitcnt vmcnt(3)" ::: "memory"); }
        else if (t + 1 < NT) { asm volatile("s_waitcnt vmcnt(0)" ::: "memory"); }
        __builtin_amdgcn_s_barrier();
        __builtin_amdgcn_sched_barrier(0);
    }

#pragma unroll
    for (int mf = 0; mf < 4; ++mf)
#pragma unroll
        for (int nf = 0; nf < 4; ++nf) {
            int gcol = n0 + wn * 64 + nf * 16 + c_lo;
            int tb = m0 + wm * 64 + mf * 16 + c_hi * 4;   // token base (multiple of 4)
            if (EPI == EPI_QKV && (n0 / 768) == 2) {
                // packed vT store: 4 consecutive tokens -> one u64
                int lcol = gcol - 2 * 768;
                int b = tb / SEQ, nt = tb % SEQ;
                int h = lcol >> 6, dh = lcol & 63;
                unsigned long long pk =
                    (unsigned long long)f2bf(acc[mf][nf][0])
                    | ((unsigned long long)f2bf(acc[mf][nf][1]) << 16)
                    | ((unsigned long long)f2bf(acc[mf][nf][2]) << 32)
                    | ((unsigned long long)f2bf(acc[mf][nf][3]) << 48);
                *(unsigned long long*)&outB3[(size_t)(((b * NHEAD + h) << 6) + dh) * SEQ + nt] = pk;
                continue;
            }
#pragma unroll
            for (int rr = 0; rr < 4; ++rr) {
                int grow = tb + rr;
                float v = acc[mf][nf][rr];
                if (EPI == EPI_CONV) {
                    v += bias[gcol]; v = fmaxf(v, 0.f);
                    outF[(size_t)grow * 768 + gcol] = v;
                } else if (EPI == EPI_QKV) {
                    int sel = n0 / 768;
                    int lcol = gcol - sel * 768;
                    if (sel == 0)      outB [(size_t)grow * 768 + lcol] = f2bf(v);
                    else               outB2[(size_t)grow * 768 + lcol] = f2bf(v);
                } else if (EPI == EPI_FFN1) {
                    v += bias[gcol]; v = fmaxf(v, 0.f);
                    outB[(size_t)grow * N + gcol] = f2bf(v);
                } else if (EPI == EPI_FFN2) {
                    outF[(size_t)grow * 768 + gcol] += v + bias[gcol];
                }
            }
        }
}

// ---------- flash attention (K/V register double-buffer + XCD grouping) ----------
__global__ __launch_bounds__(256) void attn_kernel(const u16* __restrict__ Qb,
                                                   const u16* __restrict__ Kb,
                                                   const u16* __restrict__ Vt,
                                                   float* __restrict__ T) {
    int bid = blockIdx.x;
    int qt = bid / 192, bh = bid % 192;
    int b = bh / NHEAD, h = bh % NHEAD;
    int q0 = qt * 64;
    const int tid = threadIdx.x, wave = tid >> 6, lane = tid & 63;
    const int c_lo = lane & 15, c_hi = lane >> 4;
    __shared__ __align__(16) u16 Qs[64][72];
    __shared__ __align__(16) u16 Ks[64][72];
    __shared__ __align__(16) u16 Vs[64][72];
    __shared__ __align__(16) u16 Ps[4][16][72];
#pragma unroll
    for (int i = 0; i < 2; ++i) {
        int c = i * 256 + tid, row = c >> 3, slot = (c & 7) * 8;
        *(s16x8*)&Qs[row][slot] =
            *(const s16x8*)(Qb + ((size_t)(b * SEQ + q0 + row) * DMODEL + h * HDIM + slot));
    }
    s16x8 kreg[2], vreg[2];
    {
#pragma unroll
        for (int i = 0; i < 2; ++i) {
            int c = i * 256 + tid, row = c >> 3, slot = (c & 7) * 8;
            kreg[i] = *(const s16x8*)(Kb + ((size_t)(b * SEQ + row) * DMODEL + h * HDIM + slot));
            vreg[i] = *(const s16x8*)(Vt + ((size_t)((b * NHEAD + h) * HDIM + row) * SEQ + slot));
        }
    }
    f32x4 o[4] = {};
    float mrun[4], lrun[4];
#pragma unroll
    for (int r = 0; r < 4; ++r) { mrun[r] = -1e30f; lrun[r] = 0.f; }
    for (int t2 = 0; t2 < 9; ++t2) {
        __builtin_amdgcn_s_barrier();
#pragma unroll
        for (int i = 0; i < 2; ++i) {
            int c = i * 256 + tid, row = c >> 3, slot = (c & 7) * 8;
            *(s16x8*)&Ks[row][slot] = kreg[i];
            *(s16x8*)&Vs[row][slot] = vreg[i];
        }
        asm volatile("s_waitcnt lgkmcnt(0)" ::: "memory");
        __builtin_amdgcn_s_barrier();
        __builtin_amdgcn_sched_barrier(0);
        if (t2 < 8) {
            int kv0 = (t2 + 1) * 64;
#pragma unroll
            for (int i = 0; i < 2; ++i) {
                int c = i * 256 + tid, row = c >> 3, slot = (c & 7) * 8;
                kreg[i] = *(const s16x8*)(Kb + ((size_t)(b * SEQ + kv0 + row) * DMODEL + h * HDIM + slot));
                vreg[i] = *(const s16x8*)(Vt + ((size_t)((b * NHEAD + h) * HDIM + row) * SEQ + kv0 + slot));
            }
        }
        f32x4 s[4] = {};
        s16x8 aq[2];
#pragma unroll
        for (int ks = 0; ks < 2; ++ks)
            aq[ks] = *(const s16x8*)&Qs[wave * 16 + c_lo][ks * 32 + c_hi * 8];
#pragma unroll
        for (int nf = 0; nf < 4; ++nf)
#pragma unroll
            for (int ks = 0; ks < 2; ++ks) {
                s16x8 bk = *(const s16x8*)&Ks[nf * 16 + c_lo][ks * 32 + c_hi * 8];
                s[nf] = __builtin_amdgcn_mfma_f32_16x16x32_bf16(aq[ks], bk, s[nf], 0, 0, 0);
            }
#pragma unroll
        for (int nf = 0; nf < 4; ++nf)
#pragma unroll
            for (int r = 0; r < 4; ++r) s[nf][r] *= 0.125f;
        float mx[4];
#pragma unroll
        for (int r = 0; r < 4; ++r)
            mx[r] = fmaxf(fmaxf(s[0][r], s[1][r]), fmaxf(s[2][r], s[3][r]));
#pragma unroll
        for (int off = 1; off < 16; off <<= 1)
#pragma unroll
            for (int r = 0; r < 4; ++r) mx[r] = fmaxf(mx[r], __shfl_xor(mx[r], off));
        float alpha[4];
#pragma unroll
        for (int r = 0; r < 4; ++r) {
            float mn = fmaxf(mrun[r], mx[r]);
            alpha[r] = __expf(mrun[r] - mn);
            mrun[r] = mn;
            lrun[r] *= alpha[r];
        }
        float ls[4] = {0.f, 0.f, 0.f, 0.f};
        u16 pb[4][4];
#pragma unroll
        for (int nf = 0; nf < 4; ++nf)
#pragma unroll
            for (int r = 0; r < 4; ++r) {
                float p = __expf(s[nf][r] - mrun[r]);
                ls[r] += p;
                pb[nf][r] = f2bf(p);
            }
#pragma unroll
        for (int off = 1; off < 16; off <<= 1)
#pragma unroll
            for (int r = 0; r < 4; ++r) ls[r] += __shfl_xor(ls[r], off);
#pragma unroll
        for (int r = 0; r < 4; ++r) lrun[r] += ls[r];
#pragma unroll
        for (int df = 0; df < 4; ++df)
#pragma unroll
            for (int r = 0; r < 4; ++r) o[df][r] *= alpha[r];
#pragma unroll
        for (int nf = 0; nf < 4; ++nf)
#pragma unroll
            for (int r = 0; r < 4; ++r)
                Ps[wave][c_hi * 4 + r][c_lo + nf * 16] = pb[nf][r];
        asm volatile("s_waitcnt lgkmcnt(0)" ::: "memory");
        s16x8 pa[2];
#pragma unroll
        for (int ks = 0; ks < 2; ++ks)
            pa[ks] = *(const s16x8*)&Ps[wave][c_lo][ks * 32 + c_hi * 8];
#pragma unroll
        for (int df = 0; df < 4; ++df)
#pragma unroll
            for (int ks = 0; ks < 2; ++ks) {
                s16x8 bv = *(const s16x8*)&Vs[df * 16 + c_lo][ks * 32 + c_hi * 8];
                o[df] = __builtin_amdgcn_mfma_f32_16x16x32_bf16(pa[ks], bv, o[df], 0, 0, 0);
            }
    }
#pragma unroll
    for (int df = 0; df < 4; ++df)
#pragma unroll
        for (int r = 0; r < 4; ++r) {
            int grow = b * SEQ + q0 + wave * 16 + c_hi * 4 + r;
            int gcol = h * HDIM + df * 16 + c_lo;
            T[(size_t)grow * DMODEL + gcol] += o[df][r] / lrun[r];
        }
}

// ---------- host ----------
extern "C" void kernel_launch(void* const* d_in, const int* in_sizes, int n_in,
                              void* d_out, int out_size, void* d_ws, size_t ws_size,
                              hipStream_t stream) {
    (void)in_sizes; (void)n_in; (void)out_size;
    const float* x        = (const float*)d_in[0];
    const float* conv_w   = (const float*)d_in[1];
    const float* conv_b   = (const float*)d_in[2];
    const float* ln_w     = (const float*)d_in[3];
    const float* ln_b     = (const float*)d_in[4];
    const float* pos_y    = (const float*)d_in[5];
    const float* pos_x    = (const float*)d_in[6];
    const float* mha_ln_w = (const float*)d_in[7];
    const float* mha_ln_b = (const float*)d_in[8];
    const float* qw       = (const float*)d_in[9];
    const float* kw       = (const float*)d_in[10];
    const float* vw       = (const float*)d_in[11];
    const float* ffn_ln_w = (const float*)d_in[12];
    const float* ffn_ln_b = (const float*)d_in[13];
    const float* w1       = (const float*)d_in[14];
    const float* b1       = (const float*)d_in[15];
    const float* w2       = (const float*)d_in[16];
    const float* b2       = (const float*)d_in[17];
    const int*   xs       = (const int*)d_in[18];
    const int*   ys       = (const int*)d_in[19];
    float* out1 = (float*)d_out;
    float* out2 = out1 + (size_t)NTOK * DMODEL;

    size_t off = 0;
    char* ws = (char*)d_ws;
    auto carve = [&](size_t bytes) { char* p = ws + off; off += (bytes + 255) & ~(size_t)255; return p; };
    // activations (shared by both modes)
    float* t  = (float*)carve((size_t)NTOK * DMODEL * 4);
    u16* tl   = (u16*)carve((size_t)NTOK * DMODEL * 2);
    u16* qb   = (u16*)carve((size_t)NTOK * DMODEL * 2);
    u16* kb   = (u16*)carve((size_t)NTOK * DMODEL * 2);
    u16* vT   = (u16*)carve((size_t)NTOK * DMODEL * 2);
    u16* hb   = (u16*)carve((size_t)NTOK * DFF * 2);
    float* posln = (float*)carve((size_t)SEQ * DMODEL * 4);
    // weights: all-layer (hoisted) if ws allows, else single-layer
    const size_t QKV_STRIDE = (size_t)3 * 768 * 768;
    const size_t W1_STRIDE  = (size_t)768 * DFF;
    size_t need_all = off + (QKV_STRIDE + 2 * W1_STRIDE) * 12 * 2 + 4096;
    bool hoist = (ws_size >= need_all);
    int nl = hoist ? 12 : 1;
    u16* wTqkv = (u16*)carve(QKV_STRIDE * nl * 2);
    u16* w1T   = (u16*)carve(W1_STRIDE * nl * 2);
    u16* w2T   = (u16*)carve(W1_STRIDE * nl * 2);
    u16* cw    = wTqkv;   // alias: conv weight bf16 (pre-loop only; overwritten by transpose later)
    u16* im2c  = hb;      // alias: im2col (pre-loop only)

    convert_bf16_kernel<<<1152, 256, 0, stream>>>(conv_w, cw, 768 * 768);
    im2col_kernel<<<NTOK, 256, 0, stream>>>(x, im2c);
    gemm3b<EPI_CONV><<<dim3(72, 3), 512, 0, stream>>>(im2c, cw, t, nullptr, nullptr, nullptr,
                                                      conv_b, 768, 768, 768);
    pos_ln_kernel<<<SEQ, 256, 0, stream>>>(pos_y, pos_x, ln_w, ln_b, xs, ys, posln, out2);
    ln_add_pos_kernel<<<NTOK, 256, 0, stream>>>(t, ln_w, ln_b, posln);
    if (hoist)
        transpose64_kernel<<<1584 * 12, 256, 0, stream>>>(qw, kw, vw, w1, w2,
                                                          wTqkv, w1T, w2T, QKV_STRIDE, W1_STRIDE);

    for (int i = 0; i < 12; ++i) {
        if (!hoist)
            transpose64_kernel<<<1584, 256, 0, stream>>>(
                qw + (size_t)i * 768 * 768, kw + (size_t)i * 768 * 768, vw + (size_t)i * 768 * 768,
                w1 + (size_t)i * 768 * DFF, w2 + (size_t)i * DFF * 768,
                wTqkv, w1T, w2T, 0, 0);
        u16* wq = wTqkv + (hoist ? (size_t)i * QKV_STRIDE : 0) * 1;
        u16* wf1 = w1T + (hoist ? (size_t)i * W1_STRIDE : 0);
        u16* wf2 = w2T + (hoist ? (size_t)i * W1_STRIDE : 0);
        ln_bf16_kernel<<<NTOK, 256, 0, stream>>>(t, mha_ln_w + i * DMODEL, mha_ln_b + i * DMODEL, tl);
        gemm3b<EPI_QKV><<<dim3(72, 9), 512, 0, stream>>>(tl, wq, nullptr, qb, kb, vT,
                                                         nullptr, 768, 2304, 768);
        attn_kernel<<<16 * NHEAD * 9, 256, 0, stream>>>(qb, kb, vT, t);
        ln_bf16_kernel<<<NTOK, 256, 0, stream>>>(t, ffn_ln_w + i * DMODEL, ffn_ln_b + i * DMODEL, tl);
        gemm3b<EPI_FFN1><<<dim3(72, 12), 512, 0, stream>>>(tl, wf1, nullptr, hb, nullptr, nullptr,
                                                           b1 + (size_t)i * DFF, 768, 3072, 768);
        gemm3b<EPI_FFN2><<<dim3(72, 3), 512, 0, stream>>>(hb, wf2, t, nullptr, nullptr, nullptr,
                                                          b2 + (size_t)i * DMODEL, 3072, 768, 3072);
    }
    copy_f32_kernel<<<2048, 256, 0, stream>>>(t, out1, (NTOK * DMODEL) / 4);
}